// Round 5
// baseline (453.429 us; speedup 1.0000x reference)
//
#include <hip/hip_runtime.h>
#include <math.h>

#define T_STEPS 256
#define BATCH   128
#define DIMD    512
#define NROWS   (T_STEPS * BATCH)        // 32768
#define CH      16                       // scan chunk
#define NCHUNK  (T_STEPS / CH)           // 16
#define GEMV_BLOCKS (NROWS / 4)          // 8192
#define BLOCKS_PER_CHUNK (GEMV_BLOCKS / NCHUNK)  // 512
#define WRITER_BLOCKS 258
#define GRID (2 + WRITER_BLOCKS + GEMV_BLOCKS)   // 8452

#define INV2PI  0.15915494309189535f
#define L2E     1.4426950408889634f
#define TWO_L2E 2.8853900817779268f

#define AGENT __HIP_MEMORY_SCOPE_AGENT

#if __has_builtin(__builtin_amdgcn_sinf)
#define HW_SIN(x) __builtin_amdgcn_sinf(x)   // sin(2*pi*x), x in revolutions
#else
__device__ __forceinline__ float HW_SIN(float x) { return __sinf(x * 6.283185307179586f); }
#endif
#if __has_builtin(__builtin_amdgcn_exp2f)
#define EXP2(x) __builtin_amdgcn_exp2f(x)
#else
#define EXP2(x) exp2f(x)
#endif
#if __has_builtin(__builtin_amdgcn_rcpf)
#define RCP(x) __builtin_amdgcn_rcpf(x)
#else
#define RCP(x) (1.0f / (x))
#endif

// Relaxed agent-scope ops: sc-flagged access to the coherence point,
// NO buffer_wbl2 / buffer_inv (those come from acquire/release ordering
// and caused the R4 8x regression).
__device__ __forceinline__ void  st_rlx(float* p, float v) {
    __hip_atomic_store(p, v, __ATOMIC_RELAXED, AGENT);
}
__device__ __forceinline__ float ld_rlx(const float* p) {
    return __hip_atomic_load(p, __ATOMIC_RELAXED, AGENT);
}
__device__ __forceinline__ void  st_rlx_i(int* p, int v) {
    __hip_atomic_store(p, v, __ATOMIC_RELAXED, AGENT);
}
__device__ __forceinline__ int   ld_rlx_i(const int* p) {
    return __hip_atomic_load(p, __ATOMIC_RELAXED, AGENT);
}
#define VMFENCE() asm volatile("s_waitcnt vmcnt(0)" ::: "memory")
#define CFENCE()  asm volatile("" ::: "memory")

__global__ __launch_bounds__(256) void mega(
    const float* __restrict__ inp,
    const float* __restrict__ Wf, const float* __restrict__ Wi,
    const float* __restrict__ Wg, const float* __restrict__ Wo,
    const float* __restrict__ bfp, const float* __restrict__ bip,
    const float* __restrict__ bgp, const float* __restrict__ bop,
    const float* __restrict__ Pf, const float* __restrict__ Pi,
    const float* __restrict__ Pg, const float* __restrict__ Po,
    float4* __restrict__ out4,
    float4* __restrict__ X4, float* __restrict__ Hs,
    float* __restrict__ cfin, float* __restrict__ gc,
    int* __restrict__ qflag, int* __restrict__ hProg, int* __restrict__ cnt)
{
    const int bid  = blockIdx.x;
    const int tid  = threadIdx.x;
    const int wv   = tid >> 6;
    const int lane = tid & 63;

    if (bid == 0) {
        // ============== qconsts: 4 gates, one wave each ==============
        const int g = wv;
        const float* P = (g == 0) ? Pf : (g == 1) ? Pi : (g == 2) ? Pg : Po;
        const float* W = (g == 0) ? Wf : (g == 1) ? Wi : (g == 2) ? Wg : Wo;

        __shared__ float s0r[4][256], s0i[4][256], s1r[4][256], s1i[4][256];

#pragma unroll
        for (int j = 0; j < 4; ++j) {
            const int k = lane + 64 * j;
            s0r[g][k] = (k == 0)   ? 1.0f : 0.0f;  s0i[g][k] = 0.0f;
            s1r[g][k] = (k == 128) ? 1.0f : 0.0f;  s1i[g][k] = 0.0f;
        }
        __syncthreads();

        for (int l = 0; l < 2; ++l) {
            for (int w = 0; w < 8; ++w) {
                const float phi = P[l * 24 + w * 3 + 0];
                const float th  = P[l * 24 + w * 3 + 1];
                const float om  = P[l * 24 + w * 3 + 2];
                float sh, chh; __sincosf(0.5f * th, &sh, &chh);
                float sp, cp;  __sincosf(0.5f * (phi + om), &sp, &cp);
                float sm, cm;  __sincosf(0.5f * (phi - om), &sm, &cm);
                const float m00r =  cp * chh, m00i = -sp * chh;
                const float m01r = -cm * sh,  m01i = -sm * sh;
                const float m10r =  cm * sh,  m10i = -sm * sh;
                const float m11r =  cp * chh, m11i =  sp * chh;

                const int shift = 7 - w;
                const int mask  = 1 << shift;

                float n0r[4], n0i[4], n1r[4], n1i[4];
#pragma unroll
                for (int j = 0; j < 4; ++j) {
                    const int k  = lane + 64 * j;
                    const int bit = (k >> shift) & 1;
                    const int i0 = k & ~mask, i1 = k | mask;
                    const float a0r = s0r[g][i0], a0i = s0i[g][i0];
                    const float a1r = s0r[g][i1], a1i = s0i[g][i1];
                    const float b0r = s1r[g][i0], b0i = s1i[g][i0];
                    const float b1r = s1r[g][i1], b1i = s1i[g][i1];
                    const float mr0 = bit ? m10r : m00r, mi0 = bit ? m10i : m00i;
                    const float mr1 = bit ? m11r : m01r, mi1 = bit ? m11i : m01i;
                    n0r[j] = mr0 * a0r - mi0 * a0i + mr1 * a1r - mi1 * a1i;
                    n0i[j] = mr0 * a0i + mi0 * a0r + mr1 * a1i + mi1 * a1r;
                    n1r[j] = mr0 * b0r - mi0 * b0i + mr1 * b1r - mi1 * b1i;
                    n1i[j] = mr0 * b0i + mi0 * b0r + mr1 * b1i + mi1 * b1r;
                }
                __syncthreads();
#pragma unroll
                for (int j = 0; j < 4; ++j) {
                    const int k = lane + 64 * j;
                    s0r[g][k] = n0r[j]; s0i[g][k] = n0i[j];
                    s1r[g][k] = n1r[j]; s1i[g][k] = n1i[j];
                }
                __syncthreads();
            }
            // CNOT chain permutation
            float n0r[4], n0i[4], n1r[4], n1i[4];
#pragma unroll
            for (int j = 0; j < 4; ++j) {
                int src = lane + 64 * j;
                for (int w = 6; w >= 0; --w) {
                    const int cb = (src >> (7 - w)) & 1;
                    src ^= cb << (6 - w);
                }
                n0r[j] = s0r[g][src]; n0i[j] = s0i[g][src];
                n1r[j] = s1r[g][src]; n1i[j] = s1i[g][src];
            }
            __syncthreads();
#pragma unroll
            for (int j = 0; j < 4; ++j) {
                const int k = lane + 64 * j;
                s0r[g][k] = n0r[j]; s0i[g][k] = n0i[j];
                s1r[g][k] = n1r[j]; s1i[g][k] = n1i[j];
            }
            __syncthreads();
        }

        float t00 = 0, t11 = 0, t01 = 0;
#pragma unroll
        for (int j = 0; j < 4; ++j) {
            const int k = lane + 64 * j;
            const float z = (k < 128) ? 1.0f : -1.0f;
            t00 += z * (s0r[g][k] * s0r[g][k] + s0i[g][k] * s0i[g][k]);
            t11 += z * (s1r[g][k] * s1r[g][k] + s1i[g][k] * s1i[g][k]);
            t01 += z * (s0i[g][k] * s1r[g][k] - s0r[g][k] * s1i[g][k]);
        }
        float tsw = 0;
#pragma unroll
        for (int j = 0; j < 8; ++j) tsw += W[512 + lane + 64 * j];

        for (int off = 32; off; off >>= 1) {
            t00 += __shfl_xor(t00, off);
            t11 += __shfl_xor(t11, off);
            t01 += __shfl_xor(t01, off);
            tsw += __shfl_xor(tsw, off);
        }
        if (lane == 0) {
            const float A  = 0.5f * (t00 + t11);
            const float Bc = 0.5f * (t00 - t11);
            const float Bs = -t01;
            const float R  = sqrtf(Bc * Bc + Bs * Bs);
            const float ph = atan2f(Bc, Bs) * INV2PI;
            const float sc = (g == 2) ? TWO_L2E : -L2E;
            st_rlx(&gc[4 * g + 0], sc * A);
            st_rlx(&gc[4 * g + 1], sc * R);
            st_rlx(&gc[4 * g + 2], ph);
            st_rlx(&gc[4 * g + 3], tsw * INV2PI);
        }
        VMFENCE();
        __syncthreads();
        if (tid == 0) st_rlx_i(qflag, 1);
        return;
    }

    if (bid == 1) {
        // ============== scan: 128 chains, 2 waves ==============
        if (tid >= BATCH) return;
        const int b = tid;

        while (ld_rlx_i(qflag) == 0) __builtin_amdgcn_s_sleep(1);
        CFENCE();
        float gcl[16];
#pragma unroll
        for (int j = 0; j < 16; ++j) gcl[j] = ld_rlx(&gc[j]);
        const float Af = gcl[0],  Rf = gcl[1],  phf = gcl[2],  swf = gcl[3];
        const float Ai = gcl[4],  Ri = gcl[5],  phi_ = gcl[6], swi = gcl[7];
        const float Ag = gcl[8],  Rg = gcl[9],  phg = gcl[10], swg = gcl[11];
        const float Ao = gcl[12], Ro = gcl[13], pho = gcl[14], swo = gcl[15];

        while (ld_rlx_i(&cnt[0]) < BLOCKS_PER_CHUNK) __builtin_amdgcn_s_sleep(1);
        CFENCE();

        float4 p[CH], q[CH];
#pragma unroll
        for (int j = 0; j < CH; ++j) p[j] = X4[j * BATCH + b];

        float c = 0.0f, h = 0.0f;
        for (int k = 0; k < NCHUNK; ++k) {
            const int tb = k * CH;
            if (k + 1 < NCHUNK) {
                while (ld_rlx_i(&cnt[k + 1]) < BLOCKS_PER_CHUNK)
                    __builtin_amdgcn_s_sleep(1);
                CFENCE();
            }
#pragma unroll
            for (int j = 0; j < CH; ++j) q[j] = X4[(tb + CH + j) * BATCH + b];
#pragma unroll
            for (int j = 0; j < CH; ++j) {
                const float4 xv = p[j];
                const float thf = fmaf(h, swf, xv.x + phf);
                const float thi = fmaf(h, swi, xv.y + phi_);
                const float thg = fmaf(h, swg, xv.z + phg);
                const float tho = fmaf(h, swo, xv.w + pho);
                const float Ef = fmaf(Rf, HW_SIN(thf), Af);  // = -L2E*E
                const float Ei = fmaf(Ri, HW_SIN(thi), Ai);
                const float Eg = fmaf(Rg, HW_SIN(thg), Ag);  // = 2*L2E*E
                const float Eo = fmaf(Ro, HW_SIN(tho), Ao);
                const float fg = RCP(1.0f + EXP2(Ef));
                const float ig = RCP(1.0f + EXP2(Ei));
                const float og = RCP(1.0f + EXP2(Eo));
                const float gg = 1.0f - 2.0f * RCP(EXP2(Eg) + 1.0f);
                c = fmaf(fg, c, ig * gg);
                h = og * (1.0f - 2.0f * RCP(EXP2(c * TWO_L2E) + 1.0f));
                st_rlx(&Hs[(tb + j) * BATCH + b], h);
            }
            if (k == NCHUNK - 1) st_rlx(&cfin[b], c);
            VMFENCE();
            if (lane == 0) st_rlx_i(&hProg[wv], tb + CH);
#pragma unroll
            for (int j = 0; j < CH; ++j) p[j] = q[j];
        }
        return;
    }

    if (bid < 2 + WRITER_BLOCKS) {
        // ============== writers: block handles t = bid-2, 4 quarters ==============
        const int t  = bid - 2;           // 0..257 (256=hx, 257=cx)
        const int qd = wv;                // quarter: b in [qd*32, qd*32+32)
        const int pidx = (qd < 2) ? 0 : 1;
        const int need = (t < 256) ? (t + 1) : 256;

        while (ld_rlx_i(&hProg[pidx]) < need) __builtin_amdgcn_s_sleep(4);
        CFENCE();

        const float* src = (t == 257) ? cfin
                         : (Hs + ((t >= 256 ? 255 : t) * BATCH));
        const float hv = src[qd * 32 + (lane & 31)];

        size_t base = (t < 256) ? ((size_t)t * 16384)
                    : (t == 256 ? (size_t)4194304 : (size_t)4210688);
        base += (size_t)qd * 4096;
#pragma unroll 8
        for (int j = 0; j < 64; ++j) {
            const float v = __shfl(hv, j >> 1);
            out4[base + j * 64 + lane] = make_float4(v, v, v, v);
        }
        return;
    }

    // ============== gemv: one wave per row ==============
    const int gblk = bid - (2 + WRITER_BLOCKS);     // 0..8191
    const int row  = gblk * 4 + wv;

    const float4* xr = (const float4*)(inp + (size_t)row * DIMD);
    const float4 xa = xr[lane];
    const float4 xb = xr[lane + 64];

    const float4* wfp = (const float4*)Wf;
    const float4* wip = (const float4*)Wi;
    const float4* wgp = (const float4*)Wg;
    const float4* wop = (const float4*)Wo;
    const float4 fa = wfp[lane], fb = wfp[lane + 64];
    const float4 ia = wip[lane], ib = wip[lane + 64];
    const float4 ga = wgp[lane], gb = wgp[lane + 64];
    const float4 oa = wop[lane], ob = wop[lane + 64];

    float sf = xa.x * fa.x + xa.y * fa.y + xa.z * fa.z + xa.w * fa.w
             + xb.x * fb.x + xb.y * fb.y + xb.z * fb.z + xb.w * fb.w;
    float si = xa.x * ia.x + xa.y * ia.y + xa.z * ia.z + xa.w * ia.w
             + xb.x * ib.x + xb.y * ib.y + xb.z * ib.z + xb.w * ib.w;
    float sg = xa.x * ga.x + xa.y * ga.y + xa.z * ga.z + xa.w * ga.w
             + xb.x * gb.x + xb.y * gb.y + xb.z * gb.z + xb.w * gb.w;
    float so = xa.x * oa.x + xa.y * oa.y + xa.z * oa.z + xa.w * oa.w
             + xb.x * ob.x + xb.y * ob.y + xb.z * ob.z + xb.w * ob.w;

    for (int off = 32; off; off >>= 1) {
        sf += __shfl_xor(sf, off);
        si += __shfl_xor(si, off);
        sg += __shfl_xor(sg, off);
        so += __shfl_xor(so, off);
    }
    if (lane < 4) {
        const float bias = (lane == 0) ? bfp[0] : (lane == 1) ? bip[0]
                         : (lane == 2) ? bgp[0] : bop[0];
        const float s = (lane == 0) ? sf : (lane == 1) ? si
                      : (lane == 2) ? sg : so;
        st_rlx(((float*)&X4[row]) + lane, (s + bias) * INV2PI);
    }
    VMFENCE();
    __syncthreads();
    if (tid == 0)
        __hip_atomic_fetch_add(&cnt[gblk >> 9], 1, __ATOMIC_RELAXED, AGENT);
}

extern "C" void kernel_launch(void* const* d_in, const int* in_sizes, int n_in,
                              void* d_out, int out_size, void* d_ws, size_t ws_size,
                              hipStream_t stream)
{
    const float* inp = (const float*)d_in[0];
    const float* Wf  = (const float*)d_in[1];
    const float* bfv = (const float*)d_in[2];
    const float* Pf  = (const float*)d_in[3];
    const float* Wi  = (const float*)d_in[4];
    const float* biv = (const float*)d_in[5];
    const float* Pi  = (const float*)d_in[6];
    const float* Wg  = (const float*)d_in[7];
    const float* bgv = (const float*)d_in[8];
    const float* Pg  = (const float*)d_in[9];
    const float* Wo  = (const float*)d_in[10];
    const float* bov = (const float*)d_in[11];
    const float* Po  = (const float*)d_in[12];

    float4* X4   = (float4*)d_ws;                     // NROWS + CH*BATCH
    float*  Hs   = (float*)(X4 + NROWS + CH * BATCH); // 32768
    float*  cfin = Hs + NROWS;                        // 128
    float*  gc   = cfin + BATCH;                      // 16
    int*    sync = (int*)(gc + 16);                   // qflag, hProg[2], cnt[16]
    int*    qflag = sync;
    int*    hProg = sync + 1;
    int*    cnt   = sync + 3;

    hipMemsetAsync(sync, 0, 19 * sizeof(int), stream);
    mega<<<GRID, 256, 0, stream>>>(inp, Wf, Wi, Wg, Wo,
                                   bfv, biv, bgv, bov,
                                   Pf, Pi, Pg, Po,
                                   (float4*)d_out,
                                   X4, Hs, cfin, gc, qflag, hProg, cnt);
}

// Round 6
// 66.101 us; speedup vs baseline: 6.8597x; 6.8597x over previous
//
#include <hip/hip_runtime.h>
#include <math.h>

#define T_STEPS 256
#define BATCH   128
#define DIMD    512
#define NROWS   (T_STEPS * BATCH)   // 32768
#define PF      16                  // prefetch depth / publish half-period
#define WRITER_BLOCKS 258

#define INV2PI  0.15915494309189535f
#define L2E     1.4426950408889634f
#define TWO_L2E 2.8853900817779268f

#define AGENT __HIP_MEMORY_SCOPE_AGENT

#if __has_builtin(__builtin_amdgcn_sinf)
#define HW_SIN(x) __builtin_amdgcn_sinf(x)   // sin(2*pi*x), x in revolutions
#else
__device__ __forceinline__ float HW_SIN(float x) { return __sinf(x * 6.283185307179586f); }
#endif
#if __has_builtin(__builtin_amdgcn_exp2f)
#define EXP2(x) __builtin_amdgcn_exp2f(x)
#else
#define EXP2(x) exp2f(x)
#endif
#if __has_builtin(__builtin_amdgcn_rcpf)
#define RCP(x) __builtin_amdgcn_rcpf(x)
#else
#define RCP(x) (1.0f / (x))
#endif

// Agent-scope relaxed ops (sc-flagged, straight to coherence point; no
// buffer_wbl2/buffer_inv cache maintenance).
__device__ __forceinline__ void  st_rlx(float* p, float v) {
    __hip_atomic_store(p, v, __ATOMIC_RELAXED, AGENT);
}
__device__ __forceinline__ void  st_rlx_i(int* p, int v) {
    __hip_atomic_store(p, v, __ATOMIC_RELAXED, AGENT);
}
__device__ __forceinline__ int   ld_rlx_i(const int* p) {
    return __hip_atomic_load(p, __ATOMIC_RELAXED, AGENT);
}
#define VMFENCE() asm volatile("s_waitcnt vmcnt(0)" ::: "memory")
#define CFENCE()  asm volatile("" ::: "memory")

// ---------------------------------------------------------------------------
// qconsts: 4 gates in parallel (wave g handles gate g, 4 amplitudes/lane).
// E(theta) = A + R*sin(theta + phi). Per gate (prescaled for the scan):
// gc[4g+0]=scale*A, gc[4g+1]=scale*R, gc[4g+2]=phi_rev, gc[4g+3]=sumWh/2pi
// scale = -L2E (sigmoid f,i,o) or +2*L2E (tanh g). Also zeroes hProg.
// ---------------------------------------------------------------------------
__global__ __launch_bounds__(256) void qconsts(
    const float* __restrict__ Pf, const float* __restrict__ Pi,
    const float* __restrict__ Pg, const float* __restrict__ Po,
    const float* __restrict__ Wf, const float* __restrict__ Wi,
    const float* __restrict__ Wg, const float* __restrict__ Wo,
    float* __restrict__ gc, int* __restrict__ hProg)
{
    const int g    = threadIdx.x >> 6;
    const int lane = threadIdx.x & 63;
    if (threadIdx.x == 0) { hProg[0] = 0; hProg[1] = 0; }
    const float* P = (g == 0) ? Pf : (g == 1) ? Pi : (g == 2) ? Pg : Po;
    const float* W = (g == 0) ? Wf : (g == 1) ? Wi : (g == 2) ? Wg : Wo;

    __shared__ float s0r[4][256], s0i[4][256], s1r[4][256], s1i[4][256];

#pragma unroll
    for (int j = 0; j < 4; ++j) {
        const int k = lane + 64 * j;
        s0r[g][k] = (k == 0)   ? 1.0f : 0.0f;  s0i[g][k] = 0.0f;
        s1r[g][k] = (k == 128) ? 1.0f : 0.0f;  s1i[g][k] = 0.0f;
    }
    __syncthreads();

    for (int l = 0; l < 2; ++l) {
        for (int w = 0; w < 8; ++w) {
            const float phi = P[l * 24 + w * 3 + 0];
            const float th  = P[l * 24 + w * 3 + 1];
            const float om  = P[l * 24 + w * 3 + 2];
            float sh, chh; __sincosf(0.5f * th, &sh, &chh);
            float sp, cp;  __sincosf(0.5f * (phi + om), &sp, &cp);
            float sm, cm;  __sincosf(0.5f * (phi - om), &sm, &cm);
            const float m00r =  cp * chh, m00i = -sp * chh;
            const float m01r = -cm * sh,  m01i = -sm * sh;
            const float m10r =  cm * sh,  m10i = -sm * sh;
            const float m11r =  cp * chh, m11i =  sp * chh;

            const int shift = 7 - w;
            const int mask  = 1 << shift;

            float n0r[4], n0i[4], n1r[4], n1i[4];
#pragma unroll
            for (int j = 0; j < 4; ++j) {
                const int k  = lane + 64 * j;
                const int bit = (k >> shift) & 1;
                const int i0 = k & ~mask, i1 = k | mask;
                const float a0r = s0r[g][i0], a0i = s0i[g][i0];
                const float a1r = s0r[g][i1], a1i = s0i[g][i1];
                const float b0r = s1r[g][i0], b0i = s1i[g][i0];
                const float b1r = s1r[g][i1], b1i = s1i[g][i1];
                const float mr0 = bit ? m10r : m00r, mi0 = bit ? m10i : m00i;
                const float mr1 = bit ? m11r : m01r, mi1 = bit ? m11i : m01i;
                n0r[j] = mr0 * a0r - mi0 * a0i + mr1 * a1r - mi1 * a1i;
                n0i[j] = mr0 * a0i + mi0 * a0r + mr1 * a1i + mi1 * a1r;
                n1r[j] = mr0 * b0r - mi0 * b0i + mr1 * b1r - mi1 * b1i;
                n1i[j] = mr0 * b0i + mi0 * b0r + mr1 * b1i + mi1 * b1r;
            }
            __syncthreads();
#pragma unroll
            for (int j = 0; j < 4; ++j) {
                const int k = lane + 64 * j;
                s0r[g][k] = n0r[j]; s0i[g][k] = n0i[j];
                s1r[g][k] = n1r[j]; s1i[g][k] = n1i[j];
            }
            __syncthreads();
        }
        // CNOT chain permutation
        float n0r[4], n0i[4], n1r[4], n1i[4];
#pragma unroll
        for (int j = 0; j < 4; ++j) {
            int src = lane + 64 * j;
            for (int w = 6; w >= 0; --w) {
                const int cb = (src >> (7 - w)) & 1;
                src ^= cb << (6 - w);
            }
            n0r[j] = s0r[g][src]; n0i[j] = s0i[g][src];
            n1r[j] = s1r[g][src]; n1i[j] = s1i[g][src];
        }
        __syncthreads();
#pragma unroll
        for (int j = 0; j < 4; ++j) {
            const int k = lane + 64 * j;
            s0r[g][k] = n0r[j]; s0i[g][k] = n0i[j];
            s1r[g][k] = n1r[j]; s1i[g][k] = n1i[j];
        }
        __syncthreads();
    }

    float t00 = 0, t11 = 0, t01 = 0;
#pragma unroll
    for (int j = 0; j < 4; ++j) {
        const int k = lane + 64 * j;
        const float z = (k < 128) ? 1.0f : -1.0f;
        t00 += z * (s0r[g][k] * s0r[g][k] + s0i[g][k] * s0i[g][k]);
        t11 += z * (s1r[g][k] * s1r[g][k] + s1i[g][k] * s1i[g][k]);
        t01 += z * (s0i[g][k] * s1r[g][k] - s0r[g][k] * s1i[g][k]);
    }
    float tsw = 0;
#pragma unroll
    for (int j = 0; j < 8; ++j) tsw += W[512 + lane + 64 * j];

    for (int off = 32; off; off >>= 1) {
        t00 += __shfl_xor(t00, off);
        t11 += __shfl_xor(t11, off);
        t01 += __shfl_xor(t01, off);
        tsw += __shfl_xor(tsw, off);
    }
    if (lane == 0) {
        const float A  = 0.5f * (t00 + t11);
        const float Bc = 0.5f * (t00 - t11);
        const float Bs = -t01;
        const float R  = sqrtf(Bc * Bc + Bs * Bs);
        const float ph = atan2f(Bc, Bs) * INV2PI;
        const float sc = (g == 2) ? TWO_L2E : -L2E;
        gc[4 * g + 0] = sc * A;
        gc[4 * g + 1] = sc * R;
        gc[4 * g + 2] = ph;
        gc[4 * g + 3] = tsw * INV2PI;
    }
}

// ---------------------------------------------------------------------------
// X4[t*B+b] = (f,i,g,o) sin-args in revolutions: (dot+b0)/2pi + phi_rev.
// One wave per row. (Separate kernel: gc visible via dispatch boundary.)
// ---------------------------------------------------------------------------
__global__ __launch_bounds__(256) void gemv4(
    const float* __restrict__ x,
    const float* __restrict__ Wf, const float* __restrict__ Wi,
    const float* __restrict__ Wg, const float* __restrict__ Wo,
    const float* __restrict__ bfp, const float* __restrict__ bip,
    const float* __restrict__ bgp, const float* __restrict__ bop,
    const float* __restrict__ gc,
    float4* __restrict__ X4)
{
    const int lane = threadIdx.x & 63;
    const int wid  = threadIdx.x >> 6;
    const int row  = (blockIdx.x << 2) + wid;

    const float4* xr = (const float4*)(x + (size_t)row * DIMD);
    const float4 xa = xr[lane];
    const float4 xb = xr[lane + 64];

    const float4* wfp = (const float4*)Wf;
    const float4* wip = (const float4*)Wi;
    const float4* wgp = (const float4*)Wg;
    const float4* wop = (const float4*)Wo;
    const float4 fa = wfp[lane], fb = wfp[lane + 64];
    const float4 ia = wip[lane], ib = wip[lane + 64];
    const float4 ga = wgp[lane], gb = wgp[lane + 64];
    const float4 oa = wop[lane], ob = wop[lane + 64];

    float sf = xa.x * fa.x + xa.y * fa.y + xa.z * fa.z + xa.w * fa.w
             + xb.x * fb.x + xb.y * fb.y + xb.z * fb.z + xb.w * fb.w;
    float si = xa.x * ia.x + xa.y * ia.y + xa.z * ia.z + xa.w * ia.w
             + xb.x * ib.x + xb.y * ib.y + xb.z * ib.z + xb.w * ib.w;
    float sg = xa.x * ga.x + xa.y * ga.y + xa.z * ga.z + xa.w * ga.w
             + xb.x * gb.x + xb.y * gb.y + xb.z * gb.z + xb.w * gb.w;
    float so = xa.x * oa.x + xa.y * oa.y + xa.z * oa.z + xa.w * oa.w
             + xb.x * ob.x + xb.y * ob.y + xb.z * ob.z + xb.w * ob.w;

    for (int off = 32; off; off >>= 1) {
        sf += __shfl_xor(sf, off);
        si += __shfl_xor(si, off);
        sg += __shfl_xor(sg, off);
        so += __shfl_xor(so, off);
    }
    if (lane == 0) {
        X4[row] = make_float4(fmaf(sf + bfp[0], INV2PI, gc[2]),
                              fmaf(si + bip[0], INV2PI, gc[6]),
                              fmaf(sg + bgp[0], INV2PI, gc[10]),
                              fmaf(so + bop[0], INV2PI, gc[14]));
    }
}

// ---------------------------------------------------------------------------
// Fused scan + broadcast. Grid 259 x 256.
// Block 0 (waves 0,1): LSTM recurrence, 64 chains each; publishes hProg[wv]
// every 32 steps (sc1 stores + vmcnt drain + relaxed flag).
// Blocks 1..258: writers for t = bid-1 (256=hx, 257=cx), one quarter per
// wave. DEFICIT-PROPORTIONAL sleep => ~2-4 polls per wave total (no storm).
// ---------------------------------------------------------------------------
__global__ __launch_bounds__(256) void scan_write(
    const float4* __restrict__ X4, const float* __restrict__ gc,
    float* __restrict__ Hs, float* __restrict__ cfin,
    float4* __restrict__ out4, int* __restrict__ hProg)
{
    const int bid  = blockIdx.x;
    const int wv   = threadIdx.x >> 6;
    const int lane = threadIdx.x & 63;

    if (bid == 0) {
        // ---------------- scan ----------------
        if (threadIdx.x >= BATCH) return;
        const int b = threadIdx.x;

        const float Af = gc[0],  Rf = gc[1],  swf = gc[3];
        const float Ai = gc[4],  Ri = gc[5],  swi = gc[7];
        const float Ag = gc[8],  Rg = gc[9],  swg = gc[11];
        const float Ao = gc[12], Ro = gc[13], swo = gc[15];

        float4 p[PF];
#pragma unroll
        for (int j = 0; j < PF; ++j) p[j] = X4[j * BATCH + b];

        float c = 0.0f, h = 0.0f;
        for (int tb = 0; tb < T_STEPS; tb += PF) {
#pragma unroll
            for (int j = 0; j < PF; ++j) {
                const int t = tb + j;
                const float4 xv = p[j];
                p[j] = X4[(t + PF) * BATCH + b];   // branchless refill (pad)

                const float thf = fmaf(h, swf, xv.x);
                const float thi = fmaf(h, swi, xv.y);
                const float thg = fmaf(h, swg, xv.z);
                const float tho = fmaf(h, swo, xv.w);
                const float Ef = fmaf(Rf, HW_SIN(thf), Af);  // = -L2E*E
                const float Ei = fmaf(Ri, HW_SIN(thi), Ai);
                const float Eg = fmaf(Rg, HW_SIN(thg), Ag);  // = 2*L2E*E
                const float Eo = fmaf(Ro, HW_SIN(tho), Ao);
                const float fg = RCP(1.0f + EXP2(Ef));
                const float ig = RCP(1.0f + EXP2(Ei));
                const float og = RCP(1.0f + EXP2(Eo));
                const float gg = 1.0f - 2.0f * RCP(EXP2(Eg) + 1.0f);
                c = fmaf(fg, c, ig * gg);
                const float y = RCP(EXP2(c * TWO_L2E) + 1.0f);
                h = fmaf(-2.0f * og, y, og);                  // o*tanh(c)
                st_rlx(&Hs[t * BATCH + b], h);
            }
            if (tb == T_STEPS - PF) st_rlx(&cfin[b], c);
            if (((tb + PF) & 31) == 0) {       // publish every 32 steps
                VMFENCE();
                if (lane == 0) st_rlx_i(&hProg[wv], tb + PF);
            }
        }
        return;
    }

    // ---------------- writers ----------------
    const int t  = bid - 1;           // 0..257 (256=hx, 257=cx)
    const int qd = wv;                // quarter: b in [qd*32, qd*32+32)
    const int pidx = (qd < 2) ? 0 : 1;
    const int need = (t < 256) ? (t + 1) : 256;

    int cur = ld_rlx_i(&hProg[pidx]);
    while (cur < need) {
        int chunks = ((need - cur) >> 4) + 1;  // ~1 chunk-time per 16 steps
        for (int s = 0; s < chunks; ++s) __builtin_amdgcn_s_sleep(16);
        cur = ld_rlx_i(&hProg[pidx]);
    }
    CFENCE();

    const float* src = (t == 257) ? cfin : (Hs + ((t >= 256 ? 255 : t) * BATCH));
    const float hv = src[qd * 32 + (lane & 31)];

    size_t base = (t < 256) ? ((size_t)t * 16384)
                : (t == 256 ? (size_t)4194304 : (size_t)4210688);
    base += (size_t)qd * 4096;
#pragma unroll 8
    for (int j = 0; j < 64; ++j) {
        const float v = __shfl(hv, j >> 1);
        out4[base + j * 64 + lane] = make_float4(v, v, v, v);
    }
}

extern "C" void kernel_launch(void* const* d_in, const int* in_sizes, int n_in,
                              void* d_out, int out_size, void* d_ws, size_t ws_size,
                              hipStream_t stream)
{
    const float* inp = (const float*)d_in[0];
    const float* Wf  = (const float*)d_in[1];
    const float* bfv = (const float*)d_in[2];
    const float* Pf  = (const float*)d_in[3];
    const float* Wi  = (const float*)d_in[4];
    const float* biv = (const float*)d_in[5];
    const float* Pi  = (const float*)d_in[6];
    const float* Wg  = (const float*)d_in[7];
    const float* bgv = (const float*)d_in[8];
    const float* Pg  = (const float*)d_in[9];
    const float* Wo  = (const float*)d_in[10];
    const float* bov = (const float*)d_in[11];
    const float* Po  = (const float*)d_in[12];

    float4* X4   = (float4*)d_ws;                     // NROWS + PF*BATCH
    float*  Hs   = (float*)(X4 + NROWS + PF * BATCH); // 32768
    float*  cfin = Hs + NROWS;                        // 128
    float*  gc   = cfin + BATCH;                      // 16
    int*    hProg = (int*)(gc + 16);                  // 2

    qconsts<<<1, 256, 0, stream>>>(Pf, Pi, Pg, Po, Wf, Wi, Wg, Wo, gc, hProg);
    gemv4<<<NROWS / 4, 256, 0, stream>>>(inp, Wf, Wi, Wg, Wo,
                                         bfv, biv, bgv, bov, gc, X4);
    scan_write<<<1 + WRITER_BLOCKS, 256, 0, stream>>>(X4, gc, Hs, cfin,
                                                      (float4*)d_out, hProg);
}